// Round 1
// baseline (3496.154 us; speedup 1.0000x reference)
//
#include <hip/hip_runtime.h>
#include <math.h>

#define NN 8192
#define NE 131072
#define NKT 125

// ---------------- basis ----------------
__global__ void k_basis(const float* __restrict__ pseudo,
                        float* __restrict__ basis, int* __restrict__ kidx) {
  int e = blockIdx.x * 256 + threadIdx.x;
  if (e >= NE) return;
  float s0 = pseudo[e*3+0]*4.f, s1 = pseudo[e*3+1]*4.f, s2 = pseudo[e*3+2]*4.f;
  float f0 = floorf(s0), f1 = floorf(s1), f2 = floorf(s2);
  int l0=(int)f0, l1=(int)f1, l2=(int)f2;
  float r0=s0-f0, r1=s1-f1, r2=s2-f2;
  #pragma unroll
  for (int s=0;s<8;s++){
    int b0=s&1, b1=(s>>1)&1, b2=(s>>2)&1;
    int i0=min(max(l0+b0,0),4);
    int i1=min(max(l1+b1,0),4);
    int i2=min(max(l2+b2,0),4);
    float w=(b0? r0:1.f-r0)*(b1? r1:1.f-r1)*(b2? r2:1.f-r2);
    basis[e*8+s]=w;
    kidx[e*8+s]=i0+5*i1+25*i2;
  }
}

// ---------------- counting sort by dst ----------------
__global__ void k_hist(const int* __restrict__ dst, int* __restrict__ counts) {
  int e = blockIdx.x*256 + threadIdx.x;
  if (e >= NE) return;
  atomicAdd(&counts[dst[e]], 1);
}

__global__ void k_scan(const int* __restrict__ counts, int* __restrict__ offs,
                       int* __restrict__ cursor) {
  __shared__ int lds[1024];
  int t = threadIdx.x;
  int base = t*8;
  int c[8]; int s = 0;
  #pragma unroll
  for (int j=0;j<8;j++){ c[j]=counts[base+j]; s+=c[j]; }
  lds[t]=s; __syncthreads();
  for (int o=1;o<1024;o<<=1){
    int v = (t>=o)? lds[t-o] : 0;
    __syncthreads();
    lds[t]+=v;
    __syncthreads();
  }
  int run = (t==0)? 0 : lds[t-1];
  #pragma unroll
  for (int j=0;j<8;j++){ offs[base+j]=run; cursor[base+j]=run; run+=c[j]; }
  if (t==1023) offs[NN]=run;
}

__global__ void k_place(const int* __restrict__ dst, int* __restrict__ cursor,
                        int* __restrict__ sorted) {
  int e = blockIdx.x*256 + threadIdx.x;
  if (e >= NE) return;
  int p = atomicAdd(&cursor[dst[e]], 1);
  sorted[p] = e;
}

// ---------------- build M rows (one block per node, LDS accumulate) ----------------
template<int CIN>
__global__ void k_build(const float* __restrict__ x,
                        const float* __restrict__ basis, const int* __restrict__ kidx,
                        const int* __restrict__ src, const int* __restrict__ sorted,
                        const int* __restrict__ offs, float* __restrict__ M, int lda) {
  constexpr int SZ = NKT*CIN;
  __shared__ float acc[SZ];
  int n = blockIdx.x, t = threadIdx.x;
  for (int i=t;i<SZ;i+=256) acc[i]=0.f;
  __syncthreads();
  int beg = offs[n], end = offs[n+1];
  int wv = t>>6, ln = t&63;
  for (int j=beg+wv; j<end; j+=4) {
    int e = sorted[j];
    int sv = src[e];
    float xv = (ln<CIN)? x[(size_t)sv*CIN+ln] : 0.f;
    #pragma unroll
    for (int c=0;c<8;c++){
      float b = basis[e*8+c];
      int k = kidx[e*8+c];
      if (ln<CIN) atomicAdd(&acc[k*CIN+ln], b*xv);
    }
  }
  __syncthreads();
  size_t base = (size_t)n*lda;
  for (int i=t;i<lda;i+=256) M[base+i] = (i<SZ)? acc[i] : 0.f;
}

// ---------------- root weight + bias ----------------
template<int CIN,int COUT>
__global__ void k_root(const float* __restrict__ x, const float* __restrict__ R,
                       const float* __restrict__ B, float* __restrict__ C) {
  int n = blockIdx.x, o = threadIdx.x;
  float s = B[o];
  #pragma unroll 8
  for (int i=0;i<CIN;i++) s += x[(size_t)n*CIN+i]*R[i*COUT+o];
  C[(size_t)n*COUT+o] = s;
}

// ---------------- conv GEMM: Cpart[slice] = M[rows, kslice] @ Wflat[kslice, COUT] ----------------
template<int COUT>
__global__ void k_gemm(const float* __restrict__ A, const float* __restrict__ B,
                       float* __restrict__ Cp, int K, int lda, int nsl) {
  constexpr int CPT = COUT/32;
  __shared__ float As[64][33];
  __shared__ float Bs[32][COUT];
  int rb = blockIdx.x*64;
  int sl = blockIdx.y;
  int len = (K + nsl - 1)/nsl;
  len = (len+31)&~31;              // keep kbeg 32-aligned (and 16B-aligned loads)
  int kbeg = sl*len;
  int kend = min(K, kbeg+len);
  int t = threadIdx.x;
  int c0=(t&31)*CPT, r0=(t>>5)*8;
  float acc[8][CPT];
  #pragma unroll
  for(int i=0;i<8;i++){ for(int j=0;j<CPT;j++) acc[i][j]=0.f; }
  for (int k0=kbeg; k0<kend; k0+=32) {
    #pragma unroll
    for (int q=0;q<2;q++){
      int lin=t+256*q;
      int row=lin>>3, k4=(lin&7)*4;
      int kg=k0+k4;
      if (kg+3<kend) {
        const float4 v = *reinterpret_cast<const float4*>(&A[(size_t)(rb+row)*lda+kg]);
        As[row][k4]=v.x; As[row][k4+1]=v.y; As[row][k4+2]=v.z; As[row][k4+3]=v.w;
      } else {
        #pragma unroll
        for(int u=0;u<4;u++) As[row][k4+u] = (kg+u<kend)? A[(size_t)(rb+row)*lda+kg+u] : 0.f;
      }
    }
    constexpr int BLIN = 32*COUT/4;
    for (int lin=t; lin<BLIN; lin+=256) {
      int row=lin/(COUT/4), c4=(lin%(COUT/4))*4;
      int kg=k0+row;
      if (kg<kend) {
        const float4 v = *reinterpret_cast<const float4*>(&B[(size_t)kg*COUT+c4]);
        Bs[row][c4]=v.x; Bs[row][c4+1]=v.y; Bs[row][c4+2]=v.z; Bs[row][c4+3]=v.w;
      } else {
        Bs[row][c4]=0.f; Bs[row][c4+1]=0.f; Bs[row][c4+2]=0.f; Bs[row][c4+3]=0.f;
      }
    }
    __syncthreads();
    #pragma unroll
    for (int kk=0;kk<32;kk++){
      float bv[CPT];
      #pragma unroll
      for(int j=0;j<CPT;j++) bv[j]=Bs[kk][c0+j];
      #pragma unroll
      for(int i=0;i<8;i++){
        float a=As[r0+i][kk];
        #pragma unroll
        for(int j=0;j<CPT;j++) acc[i][j]+=a*bv[j];
      }
    }
    __syncthreads();
  }
  size_t sbase=(size_t)sl*NN*COUT;
  #pragma unroll
  for(int i=0;i<8;i++)
    for(int j=0;j<CPT;j++)
      Cp[sbase+(size_t)(rb+r0+i)*COUT+c0+j]=acc[i][j];
}

// ---------------- reduce split-K partials + root, apply ELU ----------------
__global__ void k_reduce(const float* __restrict__ Cr, const float* __restrict__ Cp,
                         float* __restrict__ H, int total, int nsl) {
  int i = blockIdx.x*256 + threadIdx.x;
  if (i >= total) return;
  float v = Cr[i];
  for (int s=0;s<nsl;s++) v += Cp[(size_t)s*total+i];
  H[i] = v>0.f ? v : expm1f(v);
}

// ---------------- Linear(64,256) + ELU ----------------
__global__ void k_l1(const float* __restrict__ H, const float* __restrict__ Wm,
                     const float* __restrict__ b, float* __restrict__ O) {
  int n = blockIdx.x, o = threadIdx.x;
  float s = b[o];
  #pragma unroll 16
  for (int i=0;i<64;i++) s += H[(size_t)n*64+i]*Wm[i*256+o];
  s = s>0.f ? s : expm1f(s);
  O[(size_t)n*256+o] = s;
}

// ---------------- Linear(256,8192): tiled fp32 GEMM + bias ----------------
__global__ void k_l2(const float* __restrict__ A, const float* __restrict__ B,
                     const float* __restrict__ bias, float* __restrict__ C) {
  __shared__ float As[64][33];
  __shared__ float Bs[32][128];
  int rb = blockIdx.y*64;
  int cb = blockIdx.x*128;
  int t = threadIdx.x;
  int r0 = (t>>5)*8;
  int c0 = (t&31);
  float acc[8][4];
  #pragma unroll
  for(int i=0;i<8;i++){ for(int j=0;j<4;j++) acc[i][j]=0.f; }
  for (int k0=0;k0<256;k0+=32) {
    #pragma unroll
    for (int q=0;q<2;q++){
      int lin=t+256*q;
      int row=lin>>3, k4=(lin&7)*4;
      const float4 v = *reinterpret_cast<const float4*>(&A[(size_t)(rb+row)*256+k0+k4]);
      As[row][k4]=v.x; As[row][k4+1]=v.y; As[row][k4+2]=v.z; As[row][k4+3]=v.w;
    }
    #pragma unroll
    for (int q=0;q<4;q++){
      int lin=t+256*q;
      int row=lin>>5, c4=(lin&31)*4;
      const float4 v = *reinterpret_cast<const float4*>(&B[(size_t)(k0+row)*8192+cb+c4]);
      Bs[row][c4]=v.x; Bs[row][c4+1]=v.y; Bs[row][c4+2]=v.z; Bs[row][c4+3]=v.w;
    }
    __syncthreads();
    #pragma unroll
    for (int kk=0;kk<32;kk++){
      float bv[4];
      #pragma unroll
      for(int j=0;j<4;j++) bv[j]=Bs[kk][c0+32*j];
      #pragma unroll
      for(int i=0;i<8;i++){
        float a=As[r0+i][kk];
        #pragma unroll
        for(int j=0;j<4;j++) acc[i][j]+=a*bv[j];
      }
    }
    __syncthreads();
  }
  #pragma unroll
  for(int i=0;i<8;i++)
    for(int j=0;j<4;j++)
      C[(size_t)(rb+r0+i)*8192 + cb+c0+32*j] = acc[i][j] + bias[cb+c0+32*j];
}

// ---------------- log_softmax per row (online max/sum, 2 passes) ----------------
__global__ void k_lsm(float* __restrict__ C) {
  __shared__ float mred[256], sred[256];
  int n = blockIdx.x, t = threadIdx.x;
  float* row = C + (size_t)n*8192;
  float m = -INFINITY, s = 0.f;
  for (int j=t;j<8192;j+=256){
    float v = row[j];
    if (v > m){ s = s*expf(m-v) + 1.f; m = v; }
    else s += expf(v-m);
  }
  mred[t]=m; sred[t]=s; __syncthreads();
  for (int o=128;o>0;o>>=1){
    if (t<o){
      float m2=mred[t+o], s2=sred[t+o];
      float M=fmaxf(mred[t],m2);
      sred[t] = sred[t]*expf(mred[t]-M) + s2*expf(m2-M);
      mred[t]=M;
    }
    __syncthreads();
  }
  float lg = mred[0] + logf(sred[0]);
  for (int j=t;j<8192;j+=256) row[j] -= lg;
}

extern "C" void kernel_launch(void* const* d_in, const int* in_sizes, int n_in,
                              void* d_out, int out_size, void* d_ws, size_t ws_size,
                              hipStream_t stream) {
  (void)in_sizes; (void)n_in; (void)out_size; (void)ws_size;
  const float* x0     = (const float*)d_in[0];
  const int*   ei     = (const int*)d_in[1];
  const float* pseudo = (const float*)d_in[2];
  const float* W[6]; const float* R[6]; const float* Bb[6];
  for (int l=0;l<6;l++){
    W[l]=(const float*)d_in[3+3*l];
    R[l]=(const float*)d_in[4+3*l];
    Bb[l]=(const float*)d_in[5+3*l];
  }
  const float* L1w=(const float*)d_in[21];
  const float* L1b=(const float*)d_in[22];
  const float* L2w=(const float*)d_in[23];
  const float* L2b=(const float*)d_in[24];
  float* out = (float*)d_out;
  char* ws = (char*)d_ws;

  size_t off=0;
  auto alloc=[&](size_t bytes)->void*{
    size_t o=off; off += (bytes+511)&~511ULL; return (void*)(ws+o);
  };
  float* basis =(float*)alloc((size_t)NE*8*4);
  int*   kidx  =(int*)  alloc((size_t)NE*8*4);
  int*   sorted=(int*)  alloc((size_t)NE*4);
  int*   counts=(int*)  alloc((size_t)NN*4);
  int*   offs  =(int*)  alloc((size_t)(NN+1)*4);
  int*   cursor=(int*)  alloc((size_t)NN*4);
  float* hA    =(float*)alloc((size_t)NN*64*4);
  float* hB    =(float*)alloc((size_t)NN*64*4);
  float* h2    =(float*)alloc((size_t)NN*256*4);
  float* croot =(float*)alloc((size_t)NN*64*4);
  float* cpart =(float*)alloc((size_t)4*NN*64*4);

  const int* src = ei;
  const int* dst = ei + NE;
  float* M = out;   // d_out doubles as the M scratch until the final GEMM

  hipMemsetAsync(counts, 0, NN*4, stream);
  k_basis<<<NE/256,256,0,stream>>>(pseudo,basis,kidx);
  k_hist <<<NE/256,256,0,stream>>>(dst,counts);
  k_scan <<<1,1024,0,stream>>>(counts,offs,cursor);
  k_place<<<NE/256,256,0,stream>>>(dst,cursor,sorted);

  dim3 gg(NN/64, 4);
  // layer 1: 1 -> 32
  k_build<1><<<NN,256,0,stream>>>(x0,basis,kidx,src,sorted,offs,M,128);
  k_root<1,32><<<NN,32,0,stream>>>(x0,R[0],Bb[0],croot);
  k_gemm<32><<<gg,256,0,stream>>>(M,W[0],cpart,125,128,4);
  k_reduce<<<(NN*32)/256,256,0,stream>>>(croot,cpart,hA,NN*32,4);
  // layer 2: 32 -> 64
  k_build<32><<<NN,256,0,stream>>>(hA,basis,kidx,src,sorted,offs,M,125*32);
  k_root<32,64><<<NN,64,0,stream>>>(hA,R[1],Bb[1],croot);
  k_gemm<64><<<gg,256,0,stream>>>(M,W[1],cpart,125*32,125*32,4);
  k_reduce<<<(NN*64)/256,256,0,stream>>>(croot,cpart,hB,NN*64,4);
  // layers 3..6: 64 -> 64 (ping-pong hB -> hA -> hB -> hA -> hB)
  float* hin=hB; float* hout=hA;
  for (int l=2;l<6;l++){
    k_build<64><<<NN,256,0,stream>>>(hin,basis,kidx,src,sorted,offs,M,125*64);
    k_root<64,64><<<NN,64,0,stream>>>(hin,R[l],Bb[l],croot);
    k_gemm<64><<<gg,256,0,stream>>>(M,W[l],cpart,125*64,125*64,4);
    k_reduce<<<(NN*64)/256,256,0,stream>>>(croot,cpart,hout,NN*64,4);
    float* tmp=hin; hin=hout; hout=tmp;
  }
  // hin now holds layer-6 output [8192,64]
  k_l1<<<NN,256,0,stream>>>(hin,L1w,L1b,h2);
  dim3 g2(64,128);
  k_l2<<<g2,256,0,stream>>>(h2,L2w,L2b,out);
  k_lsm<<<NN,256,0,stream>>>(out);
}

// Round 2
// 2905.153 us; speedup vs baseline: 1.2034x; 1.2034x over previous
//
#include <hip/hip_runtime.h>
#include <math.h>

#define NN 8192
#define NE 131072
#define NKT 125

typedef __attribute__((ext_vector_type(8))) short bf16x8;
typedef __attribute__((ext_vector_type(4))) float f32x4;

__device__ inline unsigned short bf16rne(float v){
  unsigned u = __float_as_uint(v);
  u += 0x7FFF + ((u>>16)&1);
  return (unsigned short)(u>>16);
}

// ---------------- basis ----------------
__global__ void k_basis(const float* __restrict__ pseudo,
                        float* __restrict__ basis, int* __restrict__ kidx) {
  int e = blockIdx.x * 256 + threadIdx.x;
  if (e >= NE) return;
  float s0 = pseudo[e*3+0]*4.f, s1 = pseudo[e*3+1]*4.f, s2 = pseudo[e*3+2]*4.f;
  float f0 = floorf(s0), f1 = floorf(s1), f2 = floorf(s2);
  int l0=(int)f0, l1=(int)f1, l2=(int)f2;
  float r0=s0-f0, r1=s1-f1, r2=s2-f2;
  #pragma unroll
  for (int s=0;s<8;s++){
    int b0=s&1, b1=(s>>1)&1, b2=(s>>2)&1;
    int i0=min(max(l0+b0,0),4);
    int i1=min(max(l1+b1,0),4);
    int i2=min(max(l2+b2,0),4);
    float w=(b0? r0:1.f-r0)*(b1? r1:1.f-r1)*(b2? r2:1.f-r2);
    basis[e*8+s]=w;
    kidx[e*8+s]=i0+5*i1+25*i2;
  }
}

// ---------------- counting sort by dst ----------------
__global__ void k_hist(const int* __restrict__ dst, int* __restrict__ counts) {
  int e = blockIdx.x*256 + threadIdx.x;
  if (e >= NE) return;
  atomicAdd(&counts[dst[e]], 1);
}

__global__ void k_scan(const int* __restrict__ counts, int* __restrict__ offs,
                       int* __restrict__ cursor) {
  __shared__ int lds[1024];
  int t = threadIdx.x;
  int base = t*8;
  int c[8]; int s = 0;
  #pragma unroll
  for (int j=0;j<8;j++){ c[j]=counts[base+j]; s+=c[j]; }
  lds[t]=s; __syncthreads();
  for (int o=1;o<1024;o<<=1){
    int v = (t>=o)? lds[t-o] : 0;
    __syncthreads();
    lds[t]+=v;
    __syncthreads();
  }
  int run = (t==0)? 0 : lds[t-1];
  #pragma unroll
  for (int j=0;j<8;j++){ offs[base+j]=run; cursor[base+j]=run; run+=c[j]; }
  if (t==1023) offs[NN]=run;
}

__global__ void k_place(const int* __restrict__ dst, int* __restrict__ cursor,
                        int* __restrict__ sorted) {
  int e = blockIdx.x*256 + threadIdx.x;
  if (e >= NE) return;
  int p = atomicAdd(&cursor[dst[e]], 1);
  sorted[p] = e;
}

// ---------------- build M rows (one block per node, LDS accumulate) ----------------
template<int CIN>
__global__ void k_build(const float* __restrict__ x,
                        const float* __restrict__ basis, const int* __restrict__ kidx,
                        const int* __restrict__ src, const int* __restrict__ sorted,
                        const int* __restrict__ offs, float* __restrict__ M, int lda) {
  constexpr int SZ = NKT*CIN;
  __shared__ float acc[SZ];
  int n = blockIdx.x, t = threadIdx.x;
  for (int i=t;i<SZ;i+=256) acc[i]=0.f;
  __syncthreads();
  int beg = offs[n], end = offs[n+1];
  int wv = t>>6, ln = t&63;
  for (int j=beg+wv; j<end; j+=4) {
    int e = sorted[j];
    int sv = src[e];
    float xv = (ln<CIN)? x[(size_t)sv*CIN+ln] : 0.f;
    #pragma unroll
    for (int c=0;c<8;c++){
      float b = basis[e*8+c];
      int k = kidx[e*8+c];
      if (ln<CIN) atomicAdd(&acc[k*CIN+ln], b*xv);
    }
  }
  __syncthreads();
  size_t base = (size_t)n*lda;
  for (int i=t;i<lda;i+=256) M[base+i] = (i<SZ)? acc[i] : 0.f;
}

// ---------------- root weight + bias ----------------
template<int CIN,int COUT>
__global__ void k_root(const float* __restrict__ x, const float* __restrict__ R,
                       const float* __restrict__ B, float* __restrict__ C) {
  int n = blockIdx.x, o = threadIdx.x;
  float s = B[o];
  #pragma unroll 8
  for (int i=0;i<CIN;i++) s += x[(size_t)n*CIN+i]*R[i*COUT+o];
  C[(size_t)n*COUT+o] = s;
}

// ---------------- conv GEMM (split-bf16 MFMA): Cp[sl] = M[rows, kslice] @ W[kslice, BN]
// BM=128, 4 waves x (32 rows x BN cols), K-step 64, XOR-swizzled LDS.
template<int BN>
__global__ __launch_bounds__(256) void k_gconv(const float* __restrict__ A,
                                               const float* __restrict__ B,
                                               float* __restrict__ Cp,
                                               int K, int lda, int nsl) {
  __shared__ alignas(16) char smem[2*128*128 + 2*BN*128];
  char* Ahp = smem;
  char* Alp = smem + 128*128;
  char* Bhp = smem + 2*128*128;
  char* Blp = Bhp + BN*128;

  int t = threadIdx.x;
  int w = t>>6, lane = t&63;
  int lr = lane & 15, kq = lane >> 4;
  int rb = blockIdx.x*128;
  int sl = blockIdx.y;
  int len = ((K + nsl - 1)/nsl + 63) & ~63;
  int kbeg = sl*len;
  int kend = min(K, kbeg + len);

  f32x4 acc[2][BN/16];
  #pragma unroll
  for (int i=0;i<2;i++)
    #pragma unroll
    for (int j=0;j<BN/16;j++) acc[i][j] = (f32x4){0.f,0.f,0.f,0.f};

  for (int k0 = kbeg; k0 < kend; k0 += 64) {
    // ---- stage A tile [128][64] fp32 -> hi/lo bf16, swizzled ----
    #pragma unroll
    for (int q=0;q<8;q++){
      int lin = t + 256*q;
      int row = lin >> 4;
      int f4  = lin & 15;
      int kg = k0 + f4*4;
      const float* ap = A + (size_t)(rb+row)*lda + kg;
      float4 v; v.x=0.f; v.y=0.f; v.z=0.f; v.w=0.f;
      if (kg + 3 < kend) v = *(const float4*)ap;
      else {
        if (kg   < kend) v.x = ap[0];
        if (kg+1 < kend) v.y = ap[1];
        if (kg+2 < kend) v.z = ap[2];
      }
      unsigned short h[4], l[4];
      float vv[4] = {v.x, v.y, v.z, v.w};
      #pragma unroll
      for (int u=0;u<4;u++){
        unsigned short hh = bf16rne(vv[u]);
        float fh = __uint_as_float(((unsigned)hh)<<16);
        h[u]=hh; l[u]=bf16rne(vv[u]-fh);
      }
      int bo = (row*128 + f4*8) ^ ((row&7)<<4);
      *(uint2*)(Ahp + bo) = make_uint2((unsigned)h[0]|((unsigned)h[1]<<16),
                                       (unsigned)h[2]|((unsigned)h[3]<<16));
      *(uint2*)(Alp + bo) = make_uint2((unsigned)l[0]|((unsigned)l[1]<<16),
                                       (unsigned)l[2]|((unsigned)l[3]<<16));
    }
    // ---- stage B tile [64][BN] fp32 -> transposed hi/lo bf16 [BN][64], swizzled ----
    constexpr int BITER = (64*(BN/4))/256;
    #pragma unroll
    for (int q=0;q<BITER;q++){
      int lin = t + 256*q;
      int kr = lin / (BN/4);
      int c4 = (lin % (BN/4))*4;
      int kg = k0 + kr;
      float4 v; v.x=0.f; v.y=0.f; v.z=0.f; v.w=0.f;
      if (kg < kend) v = *(const float4*)&B[(size_t)kg*BN + c4];
      float vv[4] = {v.x, v.y, v.z, v.w};
      #pragma unroll
      for (int u=0;u<4;u++){
        int n = c4 + u;
        unsigned short hh = bf16rne(vv[u]);
        float fh = __uint_as_float(((unsigned)hh)<<16);
        int bo = (n*128 + kr*2) ^ ((n&7)<<4);
        *(unsigned short*)(Bhp + bo) = hh;
        *(unsigned short*)(Blp + bo) = bf16rne(vv[u]-fh);
      }
    }
    __syncthreads();
    // ---- MFMA ----
    int wrow = w*32;
    #pragma unroll
    for (int kk=0;kk<2;kk++){
      int kbyte = (kk*32 + kq*8)*2;
      bf16x8 ah[2], al[2];
      #pragma unroll
      for (int fm=0;fm<2;fm++){
        int row = wrow + fm*16 + lr;
        int bo = (row*128 + kbyte) ^ ((row&7)<<4);
        ah[fm] = *(const bf16x8*)(Ahp + bo);
        al[fm] = *(const bf16x8*)(Alp + bo);
      }
      #pragma unroll
      for (int fn=0;fn<BN/16;fn++){
        int n = fn*16 + lr;
        int bo = (n*128 + kbyte) ^ ((n&7)<<4);
        bf16x8 bh = *(const bf16x8*)(Bhp + bo);
        bf16x8 bl = *(const bf16x8*)(Blp + bo);
        #pragma unroll
        for (int fm=0;fm<2;fm++){
          acc[fm][fn] = __builtin_amdgcn_mfma_f32_16x16x32_bf16(ah[fm], bh, acc[fm][fn], 0,0,0);
          acc[fm][fn] = __builtin_amdgcn_mfma_f32_16x16x32_bf16(ah[fm], bl, acc[fm][fn], 0,0,0);
          acc[fm][fn] = __builtin_amdgcn_mfma_f32_16x16x32_bf16(al[fm], bh, acc[fm][fn], 0,0,0);
        }
      }
    }
    __syncthreads();
  }
  // ---- epilogue: write partials ----
  size_t sbase = (size_t)sl * NN * BN;
  int r0g = rb + w*32;
  #pragma unroll
  for (int fm=0;fm<2;fm++)
    #pragma unroll
    for (int fn=0;fn<BN/16;fn++)
      #pragma unroll
      for (int r=0;r<4;r++){
        int row = r0g + fm*16 + kq*4 + r;
        int col = fn*16 + lr;
        Cp[sbase + (size_t)row*BN + col] = acc[fm][fn][r];
      }
}

// ---------------- reduce split-K partials + root, apply ELU ----------------
__global__ void k_reduce(const float* __restrict__ Cr, const float* __restrict__ Cp,
                         float* __restrict__ H, int total, int nsl) {
  int i = blockIdx.x*256 + threadIdx.x;
  if (i >= total) return;
  float v = Cr[i];
  for (int s=0;s<nsl;s++) v += Cp[(size_t)s*total+i];
  H[i] = v>0.f ? v : expm1f(v);
}

// ---------------- Linear(64,256) + ELU ----------------
__global__ void k_l1(const float* __restrict__ H, const float* __restrict__ Wm,
                     const float* __restrict__ b, float* __restrict__ O) {
  int n = blockIdx.x, o = threadIdx.x;
  float s = b[o];
  #pragma unroll 16
  for (int i=0;i<64;i++) s += H[(size_t)n*64+i]*Wm[i*256+o];
  s = s>0.f ? s : expm1f(s);
  O[(size_t)n*256+o] = s;
}

// ---------------- Linear(256,8192) split-bf16 MFMA + bias + per-chunk lsm stats ----
// BM=BN=128, K=256 fixed, 4 waves in 2x2, each wave 64x64.
__global__ __launch_bounds__(256) void k_l2m(const float* __restrict__ A,
                                             const float* __restrict__ B,
                                             const float* __restrict__ bias,
                                             float* __restrict__ C,
                                             float* __restrict__ pstats) {
  __shared__ alignas(16) char smem[4*128*128];
  char* Ahp = smem;
  char* Alp = smem + 128*128;
  char* Bhp = smem + 2*128*128;
  char* Blp = smem + 3*128*128;

  int t = threadIdx.x;
  int w = t>>6, lane = t&63;
  int lr = lane & 15, kq = lane >> 4;
  int wr = w>>1, wc = w&1;
  int rb = blockIdx.y*128;
  int cb = blockIdx.x*128;

  f32x4 acc[4][4];
  #pragma unroll
  for (int i=0;i<4;i++)
    #pragma unroll
    for (int j=0;j<4;j++) acc[i][j] = (f32x4){0.f,0.f,0.f,0.f};

  for (int k0=0;k0<256;k0+=64) {
    #pragma unroll
    for (int q=0;q<8;q++){
      int lin = t + 256*q;
      int row = lin >> 4;
      int f4  = lin & 15;
      const float4 v = *(const float4*)&A[(size_t)(rb+row)*256 + k0 + f4*4];
      unsigned short h[4], l[4];
      float vv[4] = {v.x, v.y, v.z, v.w};
      #pragma unroll
      for (int u=0;u<4;u++){
        unsigned short hh = bf16rne(vv[u]);
        float fh = __uint_as_float(((unsigned)hh)<<16);
        h[u]=hh; l[u]=bf16rne(vv[u]-fh);
      }
      int bo = (row*128 + f4*8) ^ ((row&7)<<4);
      *(uint2*)(Ahp + bo) = make_uint2((unsigned)h[0]|((unsigned)h[1]<<16),
                                       (unsigned)h[2]|((unsigned)h[3]<<16));
      *(uint2*)(Alp + bo) = make_uint2((unsigned)l[0]|((unsigned)l[1]<<16),
                                       (unsigned)l[2]|((unsigned)l[3]<<16));
    }
    #pragma unroll
    for (int q=0;q<8;q++){
      int lin = t + 256*q;
      int kr = lin >> 5;
      int c4 = (lin & 31)*4;
      const float4 v = *(const float4*)&B[(size_t)(k0+kr)*8192 + cb + c4];
      float vv[4] = {v.x, v.y, v.z, v.w};
      #pragma unroll
      for (int u=0;u<4;u++){
        int n = c4 + u;
        unsigned short hh = bf16rne(vv[u]);
        float fh = __uint_as_float(((unsigned)hh)<<16);
        int bo = (n*128 + kr*2) ^ ((n&7)<<4);
        *(unsigned short*)(Bhp + bo) = hh;
        *(unsigned short*)(Blp + bo) = bf16rne(vv[u]-fh);
      }
    }
    __syncthreads();
    int wrow = wr*64, wcol = wc*64;
    #pragma unroll
    for (int kk=0;kk<2;kk++){
      int kbyte = (kk*32 + kq*8)*2;
      bf16x8 ah[4], al[4];
      #pragma unroll
      for (int fm=0;fm<4;fm++){
        int row = wrow + fm*16 + lr;
        int bo = (row*128 + kbyte) ^ ((row&7)<<4);
        ah[fm] = *(const bf16x8*)(Ahp + bo);
        al[fm] = *(const bf16x8*)(Alp + bo);
      }
      #pragma unroll
      for (int fn=0;fn<4;fn++){
        int n = wcol + fn*16 + lr;
        int bo = (n*128 + kbyte) ^ ((n&7)<<4);
        bf16x8 bh = *(const bf16x8*)(Bhp + bo);
        bf16x8 bl = *(const bf16x8*)(Blp + bo);
        #pragma unroll
        for (int fm=0;fm<4;fm++){
          acc[fm][fn] = __builtin_amdgcn_mfma_f32_16x16x32_bf16(ah[fm], bh, acc[fm][fn], 0,0,0);
          acc[fm][fn] = __builtin_amdgcn_mfma_f32_16x16x32_bf16(ah[fm], bl, acc[fm][fn], 0,0,0);
          acc[fm][fn] = __builtin_amdgcn_mfma_f32_16x16x32_bf16(al[fm], bh, acc[fm][fn], 0,0,0);
        }
      }
    }
    __syncthreads();
  }
  // ---- epilogue: bias, store, per-64col online-softmax stats ----
  int wrow = wr*64, wcol = wc*64;
  float bcol[4];
  #pragma unroll
  for (int fn=0;fn<4;fn++) bcol[fn] = bias[cb + wcol + fn*16 + lr];
  int cchunk = blockIdx.x*2 + wc;
  #pragma unroll
  for (int fm=0;fm<4;fm++){
    #pragma unroll
    for (int r=0;r<4;r++){
      int rowg = rb + wrow + fm*16 + kq*4 + r;
      float v0 = acc[fm][0][r] + bcol[0];
      float v1 = acc[fm][1][r] + bcol[1];
      float v2 = acc[fm][2][r] + bcol[2];
      float v3 = acc[fm][3][r] + bcol[3];
      size_t obase = (size_t)rowg*8192 + cb + wcol + lr;
      C[obase]      = v0;
      C[obase+16]   = v1;
      C[obase+32]   = v2;
      C[obase+48]   = v3;
      float m = fmaxf(fmaxf(v0,v1),fmaxf(v2,v3));
      #pragma unroll
      for (int mk=1;mk<16;mk<<=1) m = fmaxf(m, __shfl_xor(m, mk, 64));
      float s = __expf(v0-m)+__expf(v1-m)+__expf(v2-m)+__expf(v3-m);
      #pragma unroll
      for (int mk=1;mk<16;mk<<=1) s += __shfl_xor(s, mk, 64);
      if (lr==0){
        size_t pb = ((size_t)cchunk*NN + rowg)*2;
        pstats[pb]   = m;
        pstats[pb+1] = s;
      }
    }
  }
}

// ---------------- combine per-chunk stats -> per-row logsumexp ----------------
__global__ void k_lsmfin(const float* __restrict__ ps, float* __restrict__ lg) {
  int row = blockIdx.x*256 + threadIdx.x;
  float M = -INFINITY, S = 0.f;
  for (int c=0;c<128;c++){
    size_t pb = ((size_t)c*NN + row)*2;
    float m = ps[pb], s = ps[pb+1];
    if (m > M){ S = S*__expf(M-m) + s; M = m; }
    else S += s*__expf(m-M);
  }
  lg[row] = M + logf(S);
}

// ---------------- subtract logsumexp (vectorized) ----------------
__global__ void k_lsub(float* __restrict__ C, const float* __restrict__ lg) {
  int i = blockIdx.x*256 + threadIdx.x;      // over NN*8192/4 float4s
  float4 v = ((float4*)C)[i];
  float L = lg[i>>11];                        // 2048 float4 per row
  v.x-=L; v.y-=L; v.z-=L; v.w-=L;
  ((float4*)C)[i] = v;
}

extern "C" void kernel_launch(void* const* d_in, const int* in_sizes, int n_in,
                              void* d_out, int out_size, void* d_ws, size_t ws_size,
                              hipStream_t stream) {
  (void)in_sizes; (void)n_in; (void)out_size; (void)ws_size;
  const float* x0     = (const float*)d_in[0];
  const int*   ei     = (const int*)d_in[1];
  const float* pseudo = (const float*)d_in[2];
  const float* W[6]; const float* R[6]; const float* Bb[6];
  for (int l=0;l<6;l++){
    W[l]=(const float*)d_in[3+3*l];
    R[l]=(const float*)d_in[4+3*l];
    Bb[l]=(const float*)d_in[5+3*l];
  }
  const float* L1w=(const float*)d_in[21];
  const float* L1b=(const float*)d_in[22];
  const float* L2w=(const float*)d_in[23];
  const float* L2b=(const float*)d_in[24];
  float* out = (float*)d_out;
  char* ws = (char*)d_ws;

  size_t off=0;
  auto alloc=[&](size_t bytes)->void*{
    size_t o=off; off += (bytes+511)&~511ULL; return (void*)(ws+o);
  };
  float* basis =(float*)alloc((size_t)NE*8*4);
  int*   kidx  =(int*)  alloc((size_t)NE*8*4);
  int*   sorted=(int*)  alloc((size_t)NE*4);
  int*   counts=(int*)  alloc((size_t)NN*4);
  int*   offs  =(int*)  alloc((size_t)(NN+1)*4);
  int*   cursor=(int*)  alloc((size_t)NN*4);
  float* hA    =(float*)alloc((size_t)NN*64*4);
  float* hB    =(float*)alloc((size_t)NN*64*4);
  float* h2    =(float*)alloc((size_t)NN*256*4);
  float* croot =(float*)alloc((size_t)NN*64*4);
  float* cpart =(float*)alloc((size_t)8*NN*64*4);
  float* pstats=(float*)alloc((size_t)128*NN*2*4);
  float* lg    =(float*)alloc((size_t)NN*4);

  const int* src = ei;
  const int* dst = ei + NE;
  float* M = out;   // d_out doubles as the M scratch until the final GEMM

  hipMemsetAsync(counts, 0, NN*4, stream);
  k_basis<<<NE/256,256,0,stream>>>(pseudo,basis,kidx);
  k_hist <<<NE/256,256,0,stream>>>(dst,counts);
  k_scan <<<1,1024,0,stream>>>(counts,offs,cursor);
  k_place<<<NE/256,256,0,stream>>>(dst,cursor,sorted);

  dim3 gg(NN/128, 8);
  // layer 1: 1 -> 32
  k_build<1><<<NN,256,0,stream>>>(x0,basis,kidx,src,sorted,offs,M,128);
  k_root<1,32><<<NN,32,0,stream>>>(x0,R[0],Bb[0],croot);
  k_gconv<32><<<gg,256,0,stream>>>(M,W[0],cpart,125,128,8);
  k_reduce<<<(NN*32)/256,256,0,stream>>>(croot,cpart,hA,NN*32,8);
  // layer 2: 32 -> 64
  k_build<32><<<NN,256,0,stream>>>(hA,basis,kidx,src,sorted,offs,M,125*32);
  k_root<32,64><<<NN,64,0,stream>>>(hA,R[1],Bb[1],croot);
  k_gconv<64><<<gg,256,0,stream>>>(M,W[1],cpart,125*32,125*32,8);
  k_reduce<<<(NN*64)/256,256,0,stream>>>(croot,cpart,hB,NN*64,8);
  // layers 3..6: 64 -> 64 (ping-pong)
  float* hin=hB; float* hout=hA;
  for (int l=2;l<6;l++){
    k_build<64><<<NN,256,0,stream>>>(hin,basis,kidx,src,sorted,offs,M,125*64);
    k_root<64,64><<<NN,64,0,stream>>>(hin,R[l],Bb[l],croot);
    k_gconv<64><<<gg,256,0,stream>>>(M,W[l],cpart,125*64,125*64,8);
    k_reduce<<<(NN*64)/256,256,0,stream>>>(croot,cpart,hout,NN*64,8);
    float* tmp=hin; hin=hout; hout=tmp;
  }
  // hin holds layer-6 output [8192,64]
  k_l1<<<NN,256,0,stream>>>(hin,L1w,L1b,h2);
  dim3 g2(64,64);
  k_l2m<<<g2,256,0,stream>>>(h2,L2w,L2b,out,pstats);
  k_lsmfin<<<NN/256,256,0,stream>>>(pstats,lg);
  k_lsub<<<(NN*8192/4)/256,256,0,stream>>>(out,lg);
}